// Round 1
// baseline (256.346 us; speedup 1.0000x reference)
//
#include <hip/hip_runtime.h>
#include <math.h>

#define NA 2048
#define CD 128
#define NC ((size_t)NA * CD)

__device__ __forceinline__ float sigm(float x) { return 1.f / (1.f + __expf(-x)); }

// ---------------- LN over rows of 128 (no affine) ----------------
__global__ __launch_bounds__(256)
void ln_rows_kernel(const float* __restrict__ x, float* __restrict__ y) {
    int row = blockIdx.x * 4 + (threadIdx.x >> 6);
    int lane = threadIdx.x & 63;
    const float* xr = x + (size_t)row * CD;
    float2 v = *(const float2*)(xr + lane * 2);
    float s = v.x + v.y, sq = v.x * v.x + v.y * v.y;
#pragma unroll
    for (int m = 1; m < 64; m <<= 1) { s += __shfl_xor(s, m); sq += __shfl_xor(sq, m); }
    float mean = s * (1.f / 128.f);
    float var = sq * (1.f / 128.f) - mean * mean;
    float r = 1.f / sqrtf(var + 1e-5f);
    float2 o; o.x = (v.x - mean) * r; o.y = (v.y - mean) * r;
    *(float2*)(y + (size_t)row * CD + lane * 2) = o;
}

// ---------------- an = sig_a*LN(a)+skip_a ; tn = sig_t*LN(a)+skip_t ----------------
__global__ __launch_bounds__(256)
void an_tn_kernel(const float* __restrict__ a, const float* __restrict__ sg,
                  float* __restrict__ an, float* __restrict__ tn) {
    int row = blockIdx.x * 4 + (threadIdx.x >> 6);
    int lane = threadIdx.x & 63;
    const float* ar = a + (size_t)row * CD;
    float2 v = *(const float2*)(ar + lane * 2);
    float s = v.x + v.y, sq = v.x * v.x + v.y * v.y;
#pragma unroll
    for (int m = 1; m < 64; m <<= 1) { s += __shfl_xor(s, m); sq += __shfl_xor(sq, m); }
    float mean = s * (1.f / 128.f);
    float var = sq * (1.f / 128.f) - mean * mean;
    float r = 1.f / sqrtf(var + 1e-5f);
    float lx = (v.x - mean) * r, ly = (v.y - mean) * r;
    size_t idx = (size_t)row * CD + lane * 2;
    float2 s0 = *(const float2*)(sg + idx);
    float2 s1 = *(const float2*)(sg + NC + idx);
    float2 s2 = *(const float2*)(sg + 2 * NC + idx);
    float2 s3 = *(const float2*)(sg + 3 * NC + idx);
    float2 o;
    o.x = fmaf(s0.x, lx, s1.x); o.y = fmaf(s0.y, ly, s1.y);
    *(float2*)(an + idx) = o;
    o.x = fmaf(s2.x, lx, s3.x); o.y = fmaf(s2.y, ly, s3.y);
    *(float2*)(tn + idx) = o;
}

// ---------------- pb: LN(plm slice)*lnz_g+lnz_b @ w_pair, all 3 blocks ----------------
// pb layout: [3][64 qblk][4 h][32 q][128 kl]
__global__ __launch_bounds__(256)
void pb_kernel(const float* __restrict__ plm, const float* __restrict__ lnz_g,
               const float* __restrict__ lnz_b, const float* __restrict__ w_pair,
               float* __restrict__ pb) {
    __shared__ float gw[3][4][16];
    __shared__ float c0[3][4];
    int t = threadIdx.x;
    if (t < 12) {
        int i = t >> 2, h = t & 3;
        float c = 0.f;
        for (int cp = 0; cp < 16; ++cp) {
            float wp = w_pair[(i * 16 + cp) * 4 + h];
            gw[i][h][cp] = lnz_g[i * 16 + cp] * wp;
            c += lnz_b[i * 16 + cp] * wp;
        }
        c0[i][h] = c;
    }
    __syncthreads();
    int c = blockIdx.x;
    int p = blockIdx.y * 256 + t;
    int ql = p >> 7, kl = p & 127;
    int kstart = max(0, c * 32 - 48), kend = min(2048, c * 32 + 80);
    int k = kstart + kl;
    if (k >= kend) return;
    int q = c * 32 + ql;
    const float* row = plm + ((size_t)q * 2048 + (size_t)k) * 16;
    float x[16];
#pragma unroll
    for (int j = 0; j < 4; ++j) {
        float4 v = *(const float4*)(row + j * 4);
        x[j * 4 + 0] = v.x; x[j * 4 + 1] = v.y; x[j * 4 + 2] = v.z; x[j * 4 + 3] = v.w;
    }
    float s = 0.f, sq = 0.f;
#pragma unroll
    for (int cp = 0; cp < 16; ++cp) { s += x[cp]; sq += x[cp] * x[cp]; }
    float mean = s * (1.f / 16.f);
    float var = sq * (1.f / 16.f) - mean * mean;
    float r = 1.f / sqrtf(var + 1e-5f);
    float xn[16];
#pragma unroll
    for (int cp = 0; cp < 16; ++cp) xn[cp] = (x[cp] - mean) * r;
#pragma unroll
    for (int i = 0; i < 3; ++i)
#pragma unroll
        for (int h = 0; h < 4; ++h) {
            float d = c0[i][h];
#pragma unroll
            for (int cp = 0; cp < 16; ++cp) d = fmaf(xn[cp], gw[i][h][cp], d);
            pb[((((size_t)i * 64 + c) * 4 + h) * 32 + ql) * 128 + kl] = d;
        }
}

// ---------------- generic fp32 GEMM, M=2048 rows, K in {128,256} ----------------
// MODE 0: qkvg   W0..W3 each [K][128], D0[N][512], +bq on cols<128
// MODE 1: sigskip W0,W1: D0=sigmoid(x+b0) (cols<128), D1=x (cols>=128)
// MODE 2: gates   D0=sigmoid(x+b0), D1=sigmoid(x+b1)
// MODE 3: gated out: D0 = G0 * x   (Co=128)
// MODE 4: swiglu dual: D0 = silu(A@W0) * (A@W1), W [K][256]
// MODE 5: final: D0 = Badd + G0 * x  (Co=128, K may be 256)
template<int MODE>
__global__ __launch_bounds__(MODE == 4 ? 64 : 128)
void gemm_kernel(const float* __restrict__ A, const float* __restrict__ gammaA,
                 const float* __restrict__ W0, const float* __restrict__ W1,
                 const float* __restrict__ W2, const float* __restrict__ W3,
                 const float* __restrict__ b0, const float* __restrict__ b1,
                 const float* __restrict__ G0, const float* __restrict__ Badd,
                 float* __restrict__ D0, float* __restrict__ D1,
                 int K, int zd) {
    constexpr int BM = 32;
    constexpr int BN = (MODE == 4) ? 32 : 64;
    constexpr int NT = (MODE == 4) ? 64 : 128;
    constexpr int WLD = BN + 4;
    constexpr int ALD = BM + 1;
    constexpr int WCOLS = (MODE == 4) ? 256 : 128;

    __shared__ float At[128 * ALD];
    __shared__ float Wt[128 * WLD];
    __shared__ float Wt2[(MODE == 4) ? 128 * WLD : 4];

    const int z = blockIdx.z;
    const size_t wz = (size_t)z * (size_t)K * (size_t)WCOLS;
    W0 += wz;
    if (W1) W1 += wz;
    if (W2) W2 += wz;
    if (W3) W3 += wz;
    if (gammaA) gammaA += (size_t)z * CD;
    if (b0) b0 += (size_t)z * CD;
    if (b1) b1 += (size_t)z * CD;
    D0 += (size_t)z * (size_t)zd;
    if (D1) D1 += (size_t)z * (size_t)zd;

    const int r0 = blockIdx.x * BM;
    const int j0 = blockIdx.y * BN;

    const float* Wsel = W0;
    const float* Wsel2 = nullptr;
    int jloc = j0;
    if constexpr (MODE == 0) {
        int wi = j0 >> 7;
        Wsel = (wi == 0) ? W0 : (wi == 1) ? W1 : (wi == 2) ? W2 : W3;
        jloc = j0 & 127;
    } else if constexpr (MODE == 1 || MODE == 2) {
        Wsel = (j0 < 128) ? W0 : W1;
        jloc = j0 & 127;
    } else if constexpr (MODE == 4) {
        Wsel = W0; Wsel2 = W1;
    }

    const int tc = threadIdx.x % (BN / 4);
    const int tr = threadIdx.x / (BN / 4);

    float acc[4][4] = {};
    float acc2[(MODE == 4) ? 4 : 1][(MODE == 4) ? 4 : 1] = {};

    for (int kc = 0; kc < K; kc += 128) {
        // stage A transposed: At[k][r]
#pragma unroll
        for (int it = 0; it < (BM * 128 / 4) / NT; ++it) {
            int qi = it * NT + threadIdx.x;
            int r = qi >> 5;
            int kq = qi & 31;
            float4 av = *(const float4*)(A + (size_t)(r0 + r) * K + kc + kq * 4);
            if (gammaA) {
                float4 gv = *(const float4*)(gammaA + kc + kq * 4);
                av.x *= gv.x; av.y *= gv.y; av.z *= gv.z; av.w *= gv.w;
            }
            At[(kq * 4 + 0) * ALD + r] = av.x;
            At[(kq * 4 + 1) * ALD + r] = av.y;
            At[(kq * 4 + 2) * ALD + r] = av.z;
            At[(kq * 4 + 3) * ALD + r] = av.w;
        }
        // stage W
#pragma unroll
        for (int it = 0; it < (128 * BN / 4) / NT; ++it) {
            int qi = it * NT + threadIdx.x;
            int kk = qi / (BN / 4);
            int cq = qi % (BN / 4);
            *(float4*)(Wt + kk * WLD + cq * 4) =
                *(const float4*)(Wsel + (size_t)(kc + kk) * WCOLS + jloc + cq * 4);
            if constexpr (MODE == 4) {
                *(float4*)(Wt2 + kk * WLD + cq * 4) =
                    *(const float4*)(Wsel2 + (size_t)(kc + kk) * WCOLS + jloc + cq * 4);
            }
        }
        __syncthreads();
#pragma unroll 8
        for (int k = 0; k < 128; ++k) {
            float a0 = At[k * ALD + tr * 4 + 0];
            float a1 = At[k * ALD + tr * 4 + 1];
            float a2 = At[k * ALD + tr * 4 + 2];
            float a3 = At[k * ALD + tr * 4 + 3];
            float4 w = *(const float4*)(Wt + k * WLD + tc * 4);
            acc[0][0] = fmaf(a0, w.x, acc[0][0]); acc[0][1] = fmaf(a0, w.y, acc[0][1]);
            acc[0][2] = fmaf(a0, w.z, acc[0][2]); acc[0][3] = fmaf(a0, w.w, acc[0][3]);
            acc[1][0] = fmaf(a1, w.x, acc[1][0]); acc[1][1] = fmaf(a1, w.y, acc[1][1]);
            acc[1][2] = fmaf(a1, w.z, acc[1][2]); acc[1][3] = fmaf(a1, w.w, acc[1][3]);
            acc[2][0] = fmaf(a2, w.x, acc[2][0]); acc[2][1] = fmaf(a2, w.y, acc[2][1]);
            acc[2][2] = fmaf(a2, w.z, acc[2][2]); acc[2][3] = fmaf(a2, w.w, acc[2][3]);
            acc[3][0] = fmaf(a3, w.x, acc[3][0]); acc[3][1] = fmaf(a3, w.y, acc[3][1]);
            acc[3][2] = fmaf(a3, w.z, acc[3][2]); acc[3][3] = fmaf(a3, w.w, acc[3][3]);
            if constexpr (MODE == 4) {
                float4 u = *(const float4*)(Wt2 + k * WLD + tc * 4);
                acc2[0][0] = fmaf(a0, u.x, acc2[0][0]); acc2[0][1] = fmaf(a0, u.y, acc2[0][1]);
                acc2[0][2] = fmaf(a0, u.z, acc2[0][2]); acc2[0][3] = fmaf(a0, u.w, acc2[0][3]);
                acc2[1][0] = fmaf(a1, u.x, acc2[1][0]); acc2[1][1] = fmaf(a1, u.y, acc2[1][1]);
                acc2[1][2] = fmaf(a1, u.z, acc2[1][2]); acc2[1][3] = fmaf(a1, u.w, acc2[1][3]);
                acc2[2][0] = fmaf(a2, u.x, acc2[2][0]); acc2[2][1] = fmaf(a2, u.y, acc2[2][1]);
                acc2[2][2] = fmaf(a2, u.z, acc2[2][2]); acc2[2][3] = fmaf(a2, u.w, acc2[2][3]);
                acc2[3][0] = fmaf(a3, u.x, acc2[3][0]); acc2[3][1] = fmaf(a3, u.y, acc2[3][1]);
                acc2[3][2] = fmaf(a3, u.z, acc2[3][2]); acc2[3][3] = fmaf(a3, u.w, acc2[3][3]);
            }
        }
        __syncthreads();
    }
#pragma unroll
    for (int i = 0; i < 4; ++i) {
        int row = r0 + tr * 4 + i;
#pragma unroll
        for (int j = 0; j < 4; ++j) {
            int col = jloc + tc * 4 + j;
            float x = acc[i][j];
            if constexpr (MODE == 0) {
                int gcol = j0 + tc * 4 + j;
                if (j0 < 128) x += b0[gcol];
                D0[(size_t)row * 512 + gcol] = x;
            } else if constexpr (MODE == 1) {
                if (j0 < 128) D0[(size_t)row * CD + col] = sigm(x + b0[col]);
                else          D1[(size_t)row * CD + col] = x;
            } else if constexpr (MODE == 2) {
                if (j0 < 128) D0[(size_t)row * CD + col] = sigm(x + b0[col]);
                else          D1[(size_t)row * CD + col] = sigm(x + b1[col]);
            } else if constexpr (MODE == 3) {
                D0[(size_t)row * CD + col] = G0[(size_t)row * CD + col] * x;
            } else if constexpr (MODE == 4) {
                float u = x;
                float v = acc2[i][j];
                D0[(size_t)row * 256 + col] = (u * sigm(u)) * v;
            } else {
                D0[(size_t)row * CD + col] =
                    Badd[(size_t)row * CD + col] + G0[(size_t)row * CD + col] * x;
            }
        }
    }
}

// ---------------- neighborhood attention, one wg per (qblock c, head h) ----------------
__global__ __launch_bounds__(256)
void attn_kernel(const float* __restrict__ qkvg, const float* __restrict__ pb,
                 const float* __restrict__ atom_mask, float* __restrict__ og) {
    const int c = blockIdx.x;
    const int h = blockIdx.y;
    const int kstart = max(0, c * 32 - 48);
    const int kend = min(2048, c * 32 + 80);
    const int nk = kend - kstart;  // 80,112,128 (all multiples of 16)

    __shared__ float Kt[128 * 36];  // column-quad XOR-swizzled by (kl>>4)&7
    __shared__ float Vt[128 * 36];
    __shared__ float Qs[32 * 36];
    __shared__ float Ps[32 * 132];

    const int tid = threadIdx.x;
    {
        int q = tid >> 3, dq = tid & 7;
        float4 v = *(const float4*)(qkvg + (size_t)(c * 32 + q) * 512 + h * 32 + dq * 4);
        *(float4*)(Qs + q * 36 + dq * 4) = v;
    }
#pragma unroll
    for (int it = 0; it < 4; ++it) {
        int idx = it * 256 + tid;
        int kl = idx >> 3, dq = idx & 7;
        float4 kv = make_float4(0.f, 0.f, 0.f, 0.f);
        float4 vv = make_float4(0.f, 0.f, 0.f, 0.f);
        if (kl < nk) {
            size_t base = (size_t)(kstart + kl) * 512 + h * 32 + dq * 4;
            kv = *(const float4*)(qkvg + base + 128);
            vv = *(const float4*)(qkvg + base + 256);
        }
        int sw = (kl >> 4) & 7;
        *(float4*)(Kt + kl * 36 + ((dq ^ sw) << 2)) = kv;
        *(float4*)(Vt + kl * 36 + (dq << 2)) = vv;
    }
    __syncthreads();

    {
        const int qp = tid >> 4;  // 0..15, owns rows 2qp,2qp+1
        const int ks = tid & 15;  // 0..15, owns kl = 8ks..8ks+7
        const int q0r = qp * 2, q1r = qp * 2 + 1;
        float4 qa[8], qb[8];
#pragma unroll
        for (int dq = 0; dq < 8; ++dq) {
            qa[dq] = *(const float4*)(Qs + q0r * 36 + dq * 4);
            qb[dq] = *(const float4*)(Qs + q1r * 36 + dq * 4);
        }
        const float* pbp = pb + ((size_t)(c * 4 + h) * 32) * 128;
        float lg0[8], lg1[8];
#pragma unroll
        for (int ki = 0; ki < 8; ++ki) {
            int kl = ks * 8 + ki;
            int sw = (kl >> 4) & 7;
            float d0 = 0.f, d1 = 0.f;
#pragma unroll
            for (int dq = 0; dq < 8; ++dq) {
                float4 kv = *(const float4*)(Kt + kl * 36 + ((dq ^ sw) << 2));
                d0 += qa[dq].x * kv.x + qa[dq].y * kv.y + qa[dq].z * kv.z + qa[dq].w * kv.w;
                d1 += qb[dq].x * kv.x + qb[dq].y * kv.y + qb[dq].z * kv.z + qb[dq].w * kv.w;
            }
            if (kl < nk) {
                int k = kstart + kl;
                float mb = (atom_mask[k] - 1.f) * 1.0e9f;
                lg0[ki] = fmaf(d0, 0.17677669529663687f, pbp[(size_t)q0r * 128 + kl] + mb);
                lg1[ki] = fmaf(d1, 0.17677669529663687f, pbp[(size_t)q1r * 128 + kl] + mb);
            } else {
                lg0[ki] = -1e30f;
                lg1[ki] = -1e30f;
            }
        }
        float m0 = lg0[0], m1 = lg1[0];
#pragma unroll
        for (int ki = 1; ki < 8; ++ki) { m0 = fmaxf(m0, lg0[ki]); m1 = fmaxf(m1, lg1[ki]); }
#pragma unroll
        for (int msk = 1; msk < 16; msk <<= 1) {
            m0 = fmaxf(m0, __shfl_xor(m0, msk));
            m1 = fmaxf(m1, __shfl_xor(m1, msk));
        }
        float s0 = 0.f, s1 = 0.f;
#pragma unroll
        for (int ki = 0; ki < 8; ++ki) {
            lg0[ki] = __expf(lg0[ki] - m0); s0 += lg0[ki];
            lg1[ki] = __expf(lg1[ki] - m1); s1 += lg1[ki];
        }
#pragma unroll
        for (int msk = 1; msk < 16; msk <<= 1) {
            s0 += __shfl_xor(s0, msk);
            s1 += __shfl_xor(s1, msk);
        }
        float i0 = 1.f / s0, i1 = 1.f / s1;
        float4 w;
        w.x = lg0[0] * i0; w.y = lg0[1] * i0; w.z = lg0[2] * i0; w.w = lg0[3] * i0;
        *(float4*)(Ps + q0r * 132 + ks * 8) = w;
        w.x = lg0[4] * i0; w.y = lg0[5] * i0; w.z = lg0[6] * i0; w.w = lg0[7] * i0;
        *(float4*)(Ps + q0r * 132 + ks * 8 + 4) = w;
        w.x = lg1[0] * i1; w.y = lg1[1] * i1; w.z = lg1[2] * i1; w.w = lg1[3] * i1;
        *(float4*)(Ps + q1r * 132 + ks * 8) = w;
        w.x = lg1[4] * i1; w.y = lg1[5] * i1; w.z = lg1[6] * i1; w.w = lg1[7] * i1;
        *(float4*)(Ps + q1r * 132 + ks * 8 + 4) = w;
    }
    __syncthreads();
    {
        const int q = tid >> 3;
        const int ds = tid & 7;
        float o0 = 0.f, o1 = 0.f, o2 = 0.f, o3 = 0.f;
#pragma unroll 4
        for (int kl = 0; kl < nk; ++kl) {
            float p = Ps[q * 132 + kl];
            float4 vv = *(const float4*)(Vt + kl * 36 + ds * 4);
            o0 = fmaf(p, vv.x, o0); o1 = fmaf(p, vv.y, o1);
            o2 = fmaf(p, vv.z, o2); o3 = fmaf(p, vv.w, o3);
        }
        size_t gl = (size_t)(c * 32 + q) * 512 + 384 + h * 32 + ds * 4;
        float4 g = *(const float4*)(qkvg + gl);
        float4 ov;
        ov.x = o0 * sigm(g.x); ov.y = o1 * sigm(g.y);
        ov.z = o2 * sigm(g.z); ov.w = o3 * sigm(g.w);
        *(float4*)(og + (size_t)(c * 32 + q) * 128 + h * 32 + ds * 4) = ov;
    }
}

extern "C" void kernel_launch(void* const* d_in, const int* in_sizes, int n_in,
                              void* d_out, int out_size, void* d_ws, size_t ws_size,
                              hipStream_t stream) {
    const float* ql = (const float*)d_in[0];
    const float* cl = (const float*)d_in[1];
    const float* plm = (const float*)d_in[2];
    const float* atom_mask = (const float*)d_in[3];
    const float* attn_gamma = (const float*)d_in[4];
    const float* attn_wsig = (const float*)d_in[5];
    const float* attn_bsig = (const float*)d_in[6];
    const float* attn_wskip = (const float*)d_in[7];
    const float* wq = (const float*)d_in[8];
    const float* bq = (const float*)d_in[9];
    const float* wk = (const float*)d_in[10];
    const float* wv = (const float*)d_in[11];
    const float* lnz_g = (const float*)d_in[12];
    const float* lnz_b = (const float*)d_in[13];
    const float* w_pair = (const float*)d_in[14];
    const float* w_gate = (const float*)d_in[15];
    const float* w_out = (const float*)d_in[16];
    const float* w_ao = (const float*)d_in[17];
    const float* b_ao = (const float*)d_in[18];
    const float* tr_gamma = (const float*)d_in[19];
    const float* tr_wsig = (const float*)d_in[20];
    const float* tr_bsig = (const float*)d_in[21];
    const float* tr_wskip = (const float*)d_in[22];
    const float* w_t1 = (const float*)d_in[23];
    const float* w_t2 = (const float*)d_in[24];
    const float* w_t3 = (const float*)d_in[25];
    const float* w_to = (const float*)d_in[26];
    const float* b_to = (const float*)d_in[27];
    float* out = (float*)d_out;
    float* ws = (float*)d_ws;

    float* ln_s = ws;                // 1 NC
    float* a_buf = ws + NC;          // 1 NC
    float* an = ws + 2 * NC;         // 1 NC
    float* tn = ws + 3 * NC;         // 1 NC
    float* sg = ws + 4 * NC;         // 18 NC : [3][6][NC]
    float* qkvg = ws + 22 * NC;      // 4 NC : [N][512]
    float* og = ws + 26 * NC;        // 1 NC
    float* b_attn = ws + 27 * NC;    // 1 NC
    float* tbuf = ws + 28 * NC;      // 2 NC : [N][256]
    float* pb = ws + 30 * NC;        // 12 NC : [3][64][4][32][128]

    // ---- s-only precompute (all 3 blocks via grid.z) ----
    ln_rows_kernel<<<NA / 4, 256, 0, stream>>>(cl, ln_s);
    dim3 g1(NA / 32, 4, 3);
    gemm_kernel<1><<<g1, 128, 0, stream>>>(ln_s, attn_gamma, attn_wsig, attn_wskip,
        nullptr, nullptr, attn_bsig, nullptr, nullptr, nullptr,
        sg, sg + NC, 128, (int)(6 * NC));
    gemm_kernel<1><<<g1, 128, 0, stream>>>(ln_s, tr_gamma, tr_wsig, tr_wskip,
        nullptr, nullptr, tr_bsig, nullptr, nullptr, nullptr,
        sg + 2 * NC, sg + 3 * NC, 128, (int)(6 * NC));
    gemm_kernel<2><<<g1, 128, 0, stream>>>(cl, nullptr, w_ao, w_to,
        nullptr, nullptr, b_ao, b_to, nullptr, nullptr,
        sg + 4 * NC, sg + 5 * NC, 128, (int)(6 * NC));
    pb_kernel<<<dim3(64, 16), 256, 0, stream>>>(plm, lnz_g, lnz_b, w_pair, pb);

    // ---- residual block loop ----
    for (int i = 0; i < 3; ++i) {
        const float* a_cur = (i == 0) ? ql : a_buf;
        float* sgi = sg + (size_t)i * 6 * NC;
        an_tn_kernel<<<NA / 4, 256, 0, stream>>>(a_cur, sgi, an, tn);
        gemm_kernel<0><<<dim3(64, 8), 128, 0, stream>>>(an, nullptr,
            wq + (size_t)i * 16384, wk + (size_t)i * 16384,
            wv + (size_t)i * 16384, w_gate + (size_t)i * 16384,
            bq + (size_t)i * 128, nullptr, nullptr, nullptr,
            qkvg, nullptr, 128, 0);
        attn_kernel<<<dim3(64, 4), 256, 0, stream>>>(qkvg,
            pb + (size_t)i * 64 * 4 * 32 * 128, atom_mask, og);
        gemm_kernel<3><<<dim3(64, 2), 128, 0, stream>>>(og, nullptr,
            w_out + (size_t)i * 16384, nullptr, nullptr, nullptr,
            nullptr, nullptr, sgi + 4 * NC, nullptr,
            b_attn, nullptr, 128, 0);
        gemm_kernel<4><<<dim3(64, 8), 64, 0, stream>>>(tn, nullptr,
            w_t1 + (size_t)i * 32768, w_t2 + (size_t)i * 32768,
            nullptr, nullptr, nullptr, nullptr, nullptr, nullptr,
            tbuf, nullptr, 128, 0);
        float* dst = (i == 2) ? out : a_buf;
        gemm_kernel<5><<<dim3(64, 2), 128, 0, stream>>>(tbuf, nullptr,
            w_t3 + (size_t)i * 32768, nullptr, nullptr, nullptr,
            nullptr, nullptr, sgi + 5 * NC, b_attn,
            dst, nullptr, 256, 0);
    }
}

// Round 2
// 163.359 us; speedup vs baseline: 1.5692x; 1.5692x over previous
//
#include <hip/hip_runtime.h>
#include <math.h>

#define NA 2048
#define CD 128
#define NC ((size_t)262144)   // NA*CD

typedef unsigned short u16;
typedef short s8v __attribute__((ext_vector_type(8)));
typedef float f4v __attribute__((ext_vector_type(4)));

__device__ __forceinline__ float sigm(float x) { return 1.f / (1.f + __expf(-x)); }

__device__ __forceinline__ u16 f2bf(float x) {
    unsigned u = __float_as_uint(x);
    u += 0x7fffu + ((u >> 16) & 1u);
    return (u16)(u >> 16);
}
__device__ __forceinline__ float bf2f(u16 h) { return __uint_as_float((unsigned)h << 16); }

// ---------------- weight prep: transpose + gamma-fold + bf16 hi/lo split ----------------
// BP1 [3][768][128]  rows: 0-127 g_a*wsigA^T | 128-255 g_a*wskipA^T | 256-383 g_t*wsigT^T
//                          | 384-511 g_t*wskipT^T | 512-639 w_ao^T | 640-767 w_to^T
// BG1 [3][1024][128] rows: wq^T | wk^T | wv^T | w_gate^T | w_t1^T(256) | w_t2^T(256)
// BG2 [3][128][384]  [c][k]: k<128 w_out[k][c] else w_t3[k-128][c]
// Pbias [3][6][128]
__global__ __launch_bounds__(256)
void prep_w(const float* __restrict__ attn_gamma, const float* __restrict__ attn_wsig,
            const float* __restrict__ attn_bsig, const float* __restrict__ attn_wskip,
            const float* __restrict__ wq, const float* __restrict__ wk,
            const float* __restrict__ wv, const float* __restrict__ w_gate,
            const float* __restrict__ w_out, const float* __restrict__ w_ao,
            const float* __restrict__ b_ao,
            const float* __restrict__ tr_gamma, const float* __restrict__ tr_wsig,
            const float* __restrict__ tr_bsig, const float* __restrict__ tr_wskip,
            const float* __restrict__ w_t1, const float* __restrict__ w_t2,
            const float* __restrict__ w_t3, const float* __restrict__ w_to,
            const float* __restrict__ b_to,
            u16* __restrict__ BP1h, u16* __restrict__ BP1l,
            u16* __restrict__ BG1h, u16* __restrict__ BG1l,
            u16* __restrict__ BG2h, u16* __restrict__ BG2l,
            float* __restrict__ Pbias) {
    int e = blockIdx.x * 256 + threadIdx.x;
    if (e >= 835584) {
        int t = e - 835584;
        if (t < 2304) {
            int z = t / 768, rem = t % 768, j = rem >> 7, c = rem & 127;
            float v = 0.f;
            if (j == 0) v = attn_bsig[z * 128 + c];
            else if (j == 2) v = tr_bsig[z * 128 + c];
            else if (j == 4) v = b_ao[z * 128 + c];
            else if (j == 5) v = b_to[z * 128 + c];
            Pbias[t] = v;
        }
        return;
    }
    int z = e / 278528, r = e % 278528;
    float val;
    u16 *dh, *dl;
    size_t dofs;
    if (r < 98304) {
        int c = r >> 7, k = r & 127, seg = c >> 7, cc = c & 127;
        const float* w;
        const float* g = nullptr;
        switch (seg) {
            case 0: w = attn_wsig; g = attn_gamma; break;
            case 1: w = attn_wskip; g = attn_gamma; break;
            case 2: w = tr_wsig; g = tr_gamma; break;
            case 3: w = tr_wskip; g = tr_gamma; break;
            case 4: w = w_ao; break;
            default: w = w_to; break;
        }
        val = w[((size_t)z * 128 + k) * 128 + cc];
        if (g) val *= g[z * 128 + k];
        dh = BP1h; dl = BP1l; dofs = (size_t)z * 98304 + r;
    } else if (r < 229376) {
        int t = r - 98304, c = t >> 7, k = t & 127;
        if (c < 512) {
            int seg = c >> 7, cc = c & 127;
            const float* w = (seg == 0) ? wq : (seg == 1) ? wk : (seg == 2) ? wv : w_gate;
            val = w[((size_t)z * 128 + k) * 128 + cc];
        } else {
            int tt = c - 512;
            const float* w = (tt < 256) ? w_t1 : w_t2;
            val = w[(size_t)z * 32768 + (size_t)k * 256 + (tt & 255)];
        }
        dh = BG1h; dl = BG1l; dofs = (size_t)z * 131072 + t;
    } else {
        int t = r - 229376, c = t / 384, k = t % 384;
        val = (k < 128) ? w_out[((size_t)z * 128 + k) * 128 + c]
                        : w_t3[(size_t)z * 32768 + (size_t)(k - 128) * 128 + c];
        dh = BG2h; dl = BG2l; dofs = (size_t)z * 49152 + t;
    }
    u16 h = f2bf(val);
    dh[dofs] = h;
    dl[dofs] = f2bf(val - bf2f(h));
}

// ---------------- LN(cl) + split; also split raw cl ----------------
__global__ __launch_bounds__(256)
void ln_split(const float* __restrict__ cl, u16* __restrict__ lnsh, u16* __restrict__ lnsl,
              u16* __restrict__ clh, u16* __restrict__ cll) {
    int row = blockIdx.x * 4 + (threadIdx.x >> 6);
    int lane = threadIdx.x & 63;
    size_t idx = (size_t)row * CD + lane * 2;
    float2 v = *(const float2*)(cl + idx);
    float s = v.x + v.y, sq = v.x * v.x + v.y * v.y;
#pragma unroll
    for (int m = 1; m < 64; m <<= 1) { s += __shfl_xor(s, m); sq += __shfl_xor(sq, m); }
    float mean = s * (1.f / 128.f);
    float var = sq * (1.f / 128.f) - mean * mean;
    float r = 1.f / sqrtf(var + 1e-5f);
    float lx = (v.x - mean) * r, ly = (v.y - mean) * r;
    ushort2 h, l;
    h.x = f2bf(lx); h.y = f2bf(ly);
    l.x = f2bf(lx - bf2f(h.x)); l.y = f2bf(ly - bf2f(h.y));
    *(ushort2*)(lnsh + idx) = h; *(ushort2*)(lnsl + idx) = l;
    h.x = f2bf(v.x); h.y = f2bf(v.y);
    l.x = f2bf(v.x - bf2f(h.x)); l.y = f2bf(v.y - bf2f(h.y));
    *(ushort2*)(clh + idx) = h; *(ushort2*)(cll + idx) = l;
}

// ---------------- an/tn: LN(a) then sig*ln+skip, split to bf16 hi/lo ----------------
__global__ __launch_bounds__(256)
void an_tn(const float* __restrict__ a, const float* __restrict__ sg,
           u16* __restrict__ anh, u16* __restrict__ anl,
           u16* __restrict__ tnh, u16* __restrict__ tnl) {
    int row = blockIdx.x * 4 + (threadIdx.x >> 6);
    int lane = threadIdx.x & 63;
    size_t idx = (size_t)row * CD + lane * 2;
    float2 v = *(const float2*)(a + idx);
    float s = v.x + v.y, sq = v.x * v.x + v.y * v.y;
#pragma unroll
    for (int m = 1; m < 64; m <<= 1) { s += __shfl_xor(s, m); sq += __shfl_xor(sq, m); }
    float mean = s * (1.f / 128.f);
    float var = sq * (1.f / 128.f) - mean * mean;
    float r = 1.f / sqrtf(var + 1e-5f);
    float lx = (v.x - mean) * r, ly = (v.y - mean) * r;
    float2 s0 = *(const float2*)(sg + idx);
    float2 s1 = *(const float2*)(sg + NC + idx);
    float2 s2 = *(const float2*)(sg + 2 * NC + idx);
    float2 s3 = *(const float2*)(sg + 3 * NC + idx);
    float ax = fmaf(s0.x, lx, s1.x), ay = fmaf(s0.y, ly, s1.y);
    float tx = fmaf(s2.x, lx, s3.x), ty = fmaf(s2.y, ly, s3.y);
    ushort2 h, l;
    h.x = f2bf(ax); h.y = f2bf(ay);
    l.x = f2bf(ax - bf2f(h.x)); l.y = f2bf(ay - bf2f(h.y));
    *(ushort2*)(anh + idx) = h; *(ushort2*)(anl + idx) = l;
    h.x = f2bf(tx); h.y = f2bf(ty);
    l.x = f2bf(tx - bf2f(h.x)); l.y = f2bf(ty - bf2f(h.y));
    *(ushort2*)(tnh + idx) = h; *(ushort2*)(tnl + idx) = l;
}

// ---------------- MFMA core: 32x32 per wave, 3-term bf16 split, direct global frags ----------------
__device__ __forceinline__ void mf_core(const u16* __restrict__ Ah, const u16* __restrict__ Al,
                                        int AK, int kA,
                                        const u16* __restrict__ Bh, const u16* __restrict__ Bl,
                                        int BK, int kB,
                                        int r0, int c0, int nks, f4v (&acc)[2][2]) {
    const int lane = threadIdx.x & 63;
    const int lr = lane & 15;
    const int kg = (lane >> 4) << 3;
    const u16* pa = Ah + (size_t)(r0 + lr) * AK + kA + kg;
    const u16* pal = Al + (size_t)(r0 + lr) * AK + kA + kg;
    const u16* pb = Bh + (size_t)(c0 + lr) * BK + kB + kg;
    const u16* pbl = Bl + (size_t)(c0 + lr) * BK + kB + kg;
    const size_t aS = (size_t)16 * AK, bS = (size_t)16 * BK;
#pragma unroll
    for (int ks = 0; ks < nks; ++ks) {
        const int ko = ks * 32;
        s8v a0h = *(const s8v*)(pa + ko);
        s8v a1h = *(const s8v*)(pa + aS + ko);
        s8v a0l = *(const s8v*)(pal + ko);
        s8v a1l = *(const s8v*)(pal + aS + ko);
        s8v b0h = *(const s8v*)(pb + ko);
        s8v b1h = *(const s8v*)(pb + bS + ko);
        s8v b0l = *(const s8v*)(pbl + ko);
        s8v b1l = *(const s8v*)(pbl + bS + ko);
        acc[0][0] = __builtin_amdgcn_mfma_f32_16x16x32_bf16(a0h, b0h, acc[0][0], 0, 0, 0);
        acc[0][1] = __builtin_amdgcn_mfma_f32_16x16x32_bf16(a0h, b1h, acc[0][1], 0, 0, 0);
        acc[1][0] = __builtin_amdgcn_mfma_f32_16x16x32_bf16(a1h, b0h, acc[1][0], 0, 0, 0);
        acc[1][1] = __builtin_amdgcn_mfma_f32_16x16x32_bf16(a1h, b1h, acc[1][1], 0, 0, 0);
        acc[0][0] = __builtin_amdgcn_mfma_f32_16x16x32_bf16(a0h, b0l, acc[0][0], 0, 0, 0);
        acc[0][1] = __builtin_amdgcn_mfma_f32_16x16x32_bf16(a0h, b1l, acc[0][1], 0, 0, 0);
        acc[1][0] = __builtin_amdgcn_mfma_f32_16x16x32_bf16(a1h, b0l, acc[1][0], 0, 0, 0);
        acc[1][1] = __builtin_amdgcn_mfma_f32_16x16x32_bf16(a1h, b1l, acc[1][1], 0, 0, 0);
        acc[0][0] = __builtin_amdgcn_mfma_f32_16x16x32_bf16(a0l, b0h, acc[0][0], 0, 0, 0);
        acc[0][1] = __builtin_amdgcn_mfma_f32_16x16x32_bf16(a0l, b1h, acc[0][1], 0, 0, 0);
        acc[1][0] = __builtin_amdgcn_mfma_f32_16x16x32_bf16(a1l, b0h, acc[1][0], 0, 0, 0);
        acc[1][1] = __builtin_amdgcn_mfma_f32_16x16x32_bf16(a1l, b1h, acc[1][1], 0, 0, 0);
    }
}

// ---------------- P1: sg[z][0..5] = adaLN sig/skip pairs + output gates ----------------
__global__ __launch_bounds__(256)
void mf_p1(const u16* __restrict__ lnsh, const u16* __restrict__ lnsl,
           const u16* __restrict__ clh, const u16* __restrict__ cll,
           const u16* __restrict__ BP1h, const u16* __restrict__ BP1l,
           const float* __restrict__ Pbias, float* __restrict__ sg) {
    const int z = blockIdx.z, chunk = blockIdx.y;
    const int r0 = blockIdx.x * 32;
    const int c0 = (threadIdx.x >> 6) * 32;
    const u16* Ah = (chunk < 4) ? lnsh : clh;
    const u16* Al = (chunk < 4) ? lnsl : cll;
    const size_t bo = (size_t)z * 98304 + (size_t)chunk * 16384;
    f4v acc[2][2] = {};
    mf_core(Ah, Al, 128, 0, BP1h + bo, BP1l + bo, 128, 0, r0, c0, 4, acc);
    const bool dosig = (chunk != 1) && (chunk != 3);
    const float* bp = Pbias + (z * 6 + chunk) * 128;
    float* dst = sg + ((size_t)z * 6 + chunk) * NC;
    const int lane = threadIdx.x & 63;
    const int lr = lane & 15, rb = (lane >> 4) * 4;
#pragma unroll
    for (int mi = 0; mi < 2; ++mi)
#pragma unroll
        for (int i = 0; i < 4; ++i) {
            int row = r0 + mi * 16 + rb + i;
#pragma unroll
            for (int ni = 0; ni < 2; ++ni) {
                int col = c0 + ni * 16 + lr;
                float x = acc[mi][ni][i];
                if (dosig) x = sigm(x + bp[col]);
                dst[(size_t)row * CD + col] = x;
            }
        }
}

// ---------------- G1: qkvg (chunks 0-3, A=an) and t1|t2 (chunks 4-7, A=tn) ----------------
__global__ __launch_bounds__(256)
void mf_g1(const u16* __restrict__ anh, const u16* __restrict__ anl,
           const u16* __restrict__ tnh, const u16* __restrict__ tnl,
           const u16* __restrict__ Bh, const u16* __restrict__ Bl,
           const float* __restrict__ bq, float* __restrict__ qkvg, float* __restrict__ tbuf) {
    const int chunk = blockIdx.y;
    const int r0 = blockIdx.x * 32;
    const int c0 = (threadIdx.x >> 6) * 32;
    const u16* Ah = (chunk < 4) ? anh : tnh;
    const u16* Al = (chunk < 4) ? anl : tnl;
    const size_t bo = (size_t)chunk * 16384;
    f4v acc[2][2] = {};
    mf_core(Ah, Al, 128, 0, Bh + bo, Bl + bo, 128, 0, r0, c0, 4, acc);
    float* dst;
    int cb;
    if (chunk < 4) { dst = qkvg; cb = chunk * 128; } else { dst = tbuf; cb = (chunk - 4) * 128; }
    const int lane = threadIdx.x & 63;
    const int lr = lane & 15, rb = (lane >> 4) * 4;
#pragma unroll
    for (int mi = 0; mi < 2; ++mi)
#pragma unroll
        for (int i = 0; i < 4; ++i) {
            int row = r0 + mi * 16 + rb + i;
#pragma unroll
            for (int ni = 0; ni < 2; ++ni) {
                int col = c0 + ni * 16 + lr;
                float x = acc[mi][ni][i];
                if (chunk == 0) x += bq[col];
                dst[(size_t)row * 512 + cb + col] = x;
            }
        }
}

// ---------------- G2: a_next = sg4 * (og@w_out) + sg5 * (sw@w_t3) ----------------
__global__ __launch_bounds__(256)
void mf_g2(const u16* __restrict__ ogh, const u16* __restrict__ ogl,
           const u16* __restrict__ swh, const u16* __restrict__ swl,
           const u16* __restrict__ Bh, const u16* __restrict__ Bl,
           const float* __restrict__ sg4, const float* __restrict__ sg5,
           float* __restrict__ dst) {
    const int r0 = blockIdx.x * 32;
    const int c0 = (threadIdx.x >> 6) * 32;
    f4v acc1[2][2] = {}, acc2[2][2] = {};
    mf_core(ogh, ogl, 128, 0, Bh, Bl, 384, 0, r0, c0, 4, acc1);
    mf_core(swh, swl, 256, 0, Bh, Bl, 384, 128, r0, c0, 8, acc2);
    const int lane = threadIdx.x & 63;
    const int lr = lane & 15, rb = (lane >> 4) * 4;
#pragma unroll
    for (int mi = 0; mi < 2; ++mi)
#pragma unroll
        for (int i = 0; i < 4; ++i) {
            int row = r0 + mi * 16 + rb + i;
#pragma unroll
            for (int ni = 0; ni < 2; ++ni) {
                int col = c0 + ni * 16 + lr;
                size_t idx = (size_t)row * CD + col;
                dst[idx] = sg4[idx] * acc1[mi][ni][i] + sg5[idx] * acc2[mi][ni][i];
            }
        }
}

// ---------------- pb: LN(plm slice)*lnz_g+lnz_b @ w_pair, all 3 blocks ----------------
__global__ __launch_bounds__(256)
void pb_kernel(const float* __restrict__ plm, const float* __restrict__ lnz_g,
               const float* __restrict__ lnz_b, const float* __restrict__ w_pair,
               float* __restrict__ pb) {
    __shared__ float gw[3][4][16];
    __shared__ float c0[3][4];
    int t = threadIdx.x;
    if (t < 12) {
        int i = t >> 2, h = t & 3;
        float c = 0.f;
        for (int cp = 0; cp < 16; ++cp) {
            float wp = w_pair[(i * 16 + cp) * 4 + h];
            gw[i][h][cp] = lnz_g[i * 16 + cp] * wp;
            c += lnz_b[i * 16 + cp] * wp;
        }
        c0[i][h] = c;
    }
    __syncthreads();
    int c = blockIdx.x;
    int p = blockIdx.y * 256 + t;
    int ql = p >> 7, kl = p & 127;
    int kstart = max(0, c * 32 - 48), kend = min(2048, c * 32 + 80);
    int k = kstart + kl;
    if (k >= kend) return;
    int q = c * 32 + ql;
    const float* row = plm + ((size_t)q * 2048 + (size_t)k) * 16;
    float x[16];
#pragma unroll
    for (int j = 0; j < 4; ++j) {
        float4 v = *(const float4*)(row + j * 4);
        x[j * 4 + 0] = v.x; x[j * 4 + 1] = v.y; x[j * 4 + 2] = v.z; x[j * 4 + 3] = v.w;
    }
    float s = 0.f, sq = 0.f;
#pragma unroll
    for (int cp = 0; cp < 16; ++cp) { s += x[cp]; sq += x[cp] * x[cp]; }
    float mean = s * (1.f / 16.f);
    float var = sq * (1.f / 16.f) - mean * mean;
    float r = 1.f / sqrtf(var + 1e-5f);
    float xn[16];
#pragma unroll
    for (int cp = 0; cp < 16; ++cp) xn[cp] = (x[cp] - mean) * r;
#pragma unroll
    for (int i = 0; i < 3; ++i)
#pragma unroll
        for (int h = 0; h < 4; ++h) {
            float d = c0[i][h];
#pragma unroll
            for (int cp = 0; cp < 16; ++cp) d = fmaf(xn[cp], gw[i][h][cp], d);
            pb[((((size_t)i * 64 + c) * 4 + h) * 32 + ql) * 128 + kl] = d;
        }
}

// ---------------- neighborhood attention (y<4) + swiglu (y=4,5) ----------------
__global__ __launch_bounds__(256)
void attn_sw(const float* __restrict__ qkvg, const float* __restrict__ pb,
             const float* __restrict__ atom_mask, const float* __restrict__ tbuf,
             u16* __restrict__ ogh, u16* __restrict__ ogl,
             u16* __restrict__ swh, u16* __restrict__ swl) {
    const int c = blockIdx.x;
    const int tid = threadIdx.x;
    if (blockIdx.y >= 4) {
        // swiglu: sw = silu(t1)*t2, split to bf16 hi/lo
        const int r0 = c * 32;
        const int cb = (blockIdx.y - 4) * 128 + (tid & 31) * 4;
#pragma unroll
        for (int p = 0; p < 4; ++p) {
            int r = r0 + p * 8 + (tid >> 5);
            float4 x1 = *(const float4*)(tbuf + (size_t)r * 512 + cb);
            float4 x2 = *(const float4*)(tbuf + (size_t)r * 512 + 256 + cb);
            float4 s;
            s.x = x1.x * sigm(x1.x) * x2.x;
            s.y = x1.y * sigm(x1.y) * x2.y;
            s.z = x1.z * sigm(x1.z) * x2.z;
            s.w = x1.w * sigm(x1.w) * x2.w;
            size_t o = (size_t)r * 256 + cb;
            ushort4 h, l;
            h.x = f2bf(s.x); l.x = f2bf(s.x - bf2f(h.x));
            h.y = f2bf(s.y); l.y = f2bf(s.y - bf2f(h.y));
            h.z = f2bf(s.z); l.z = f2bf(s.z - bf2f(h.z));
            h.w = f2bf(s.w); l.w = f2bf(s.w - bf2f(h.w));
            *(ushort4*)(swh + o) = h;
            *(ushort4*)(swl + o) = l;
        }
        return;
    }
    const int h = blockIdx.y;
    const int kstart = max(0, c * 32 - 48);
    const int kend = min(2048, c * 32 + 80);
    const int nk = kend - kstart;

    __shared__ float Kt[128 * 36];
    __shared__ float Vt[128 * 36];
    __shared__ float Qs[32 * 36];
    __shared__ float Ps[32 * 132];

    {
        int q = tid >> 3, dq = tid & 7;
        float4 v = *(const float4*)(qkvg + (size_t)(c * 32 + q) * 512 + h * 32 + dq * 4);
        *(float4*)(Qs + q * 36 + dq * 4) = v;
    }
#pragma unroll
    for (int it = 0; it < 4; ++it) {
        int idx = it * 256 + tid;
        int kl = idx >> 3, dq = idx & 7;
        float4 kv = make_float4(0.f, 0.f, 0.f, 0.f);
        float4 vv = make_float4(0.f, 0.f, 0.f, 0.f);
        if (kl < nk) {
            size_t base = (size_t)(kstart + kl) * 512 + h * 32 + dq * 4;
            kv = *(const float4*)(qkvg + base + 128);
            vv = *(const float4*)(qkvg + base + 256);
        }
        int sw = (kl >> 4) & 7;
        *(float4*)(Kt + kl * 36 + ((dq ^ sw) << 2)) = kv;
        *(float4*)(Vt + kl * 36 + (dq << 2)) = vv;
    }
    __syncthreads();

    {
        const int qp = tid >> 4;
        const int ks = tid & 15;
        const int q0r = qp * 2, q1r = qp * 2 + 1;
        float4 qa[8], qb[8];
#pragma unroll
        for (int dq = 0; dq < 8; ++dq) {
            qa[dq] = *(const float4*)(Qs + q0r * 36 + dq * 4);
            qb[dq] = *(const float4*)(Qs + q1r * 36 + dq * 4);
        }
        const float* pbp = pb + ((size_t)(c * 4 + h) * 32) * 128;
        float lg0[8], lg1[8];
#pragma unroll
        for (int ki = 0; ki < 8; ++ki) {
            int kl = ks * 8 + ki;
            int sw = (kl >> 4) & 7;
            float d0 = 0.f, d1 = 0.f;
#pragma unroll
            for (int dq = 0; dq < 8; ++dq) {
                float4 kv = *(const float4*)(Kt + kl * 36 + ((dq ^ sw) << 2));
                d0 += qa[dq].x * kv.x + qa[dq].y * kv.y + qa[dq].z * kv.z + qa[dq].w * kv.w;
                d1 += qb[dq].x * kv.x + qb[dq].y * kv.y + qb[dq].z * kv.z + qb[dq].w * kv.w;
            }
            if (kl < nk) {
                int k = kstart + kl;
                float mb = (atom_mask[k] - 1.f) * 1.0e9f;
                lg0[ki] = fmaf(d0, 0.17677669529663687f, pbp[(size_t)q0r * 128 + kl] + mb);
                lg1[ki] = fmaf(d1, 0.17677669529663687f, pbp[(size_t)q1r * 128 + kl] + mb);
            } else {
                lg0[ki] = -1e30f;
                lg1[ki] = -1e30f;
            }
        }
        float m0 = lg0[0], m1 = lg1[0];
#pragma unroll
        for (int ki = 1; ki < 8; ++ki) { m0 = fmaxf(m0, lg0[ki]); m1 = fmaxf(m1, lg1[ki]); }
#pragma unroll
        for (int msk = 1; msk < 16; msk <<= 1) {
            m0 = fmaxf(m0, __shfl_xor(m0, msk));
            m1 = fmaxf(m1, __shfl_xor(m1, msk));
        }
        float s0 = 0.f, s1 = 0.f;
#pragma unroll
        for (int ki = 0; ki < 8; ++ki) {
            lg0[ki] = __expf(lg0[ki] - m0); s0 += lg0[ki];
            lg1[ki] = __expf(lg1[ki] - m1); s1 += lg1[ki];
        }
#pragma unroll
        for (int msk = 1; msk < 16; msk <<= 1) {
            s0 += __shfl_xor(s0, msk);
            s1 += __shfl_xor(s1, msk);
        }
        float i0 = 1.f / s0, i1 = 1.f / s1;
        float4 w;
        w.x = lg0[0] * i0; w.y = lg0[1] * i0; w.z = lg0[2] * i0; w.w = lg0[3] * i0;
        *(float4*)(Ps + q0r * 132 + ks * 8) = w;
        w.x = lg0[4] * i0; w.y = lg0[5] * i0; w.z = lg0[6] * i0; w.w = lg0[7] * i0;
        *(float4*)(Ps + q0r * 132 + ks * 8 + 4) = w;
        w.x = lg1[0] * i1; w.y = lg1[1] * i1; w.z = lg1[2] * i1; w.w = lg1[3] * i1;
        *(float4*)(Ps + q1r * 132 + ks * 8) = w;
        w.x = lg1[4] * i1; w.y = lg1[5] * i1; w.z = lg1[6] * i1; w.w = lg1[7] * i1;
        *(float4*)(Ps + q1r * 132 + ks * 8 + 4) = w;
    }
    __syncthreads();
    {
        const int q = tid >> 3;
        const int ds = tid & 7;
        float o0 = 0.f, o1 = 0.f, o2 = 0.f, o3 = 0.f;
#pragma unroll 4
        for (int kl = 0; kl < nk; ++kl) {
            float p = Ps[q * 132 + kl];
            float4 vv = *(const float4*)(Vt + kl * 36 + ds * 4);
            o0 = fmaf(p, vv.x, o0); o1 = fmaf(p, vv.y, o1);
            o2 = fmaf(p, vv.z, o2); o3 = fmaf(p, vv.w, o3);
        }
        size_t gl = (size_t)(c * 32 + q) * 512 + 384 + h * 32 + ds * 4;
        float4 g = *(const float4*)(qkvg + gl);
        float4 ov;
        ov.x = o0 * sigm(g.x); ov.y = o1 * sigm(g.y);
        ov.z = o2 * sigm(g.z); ov.w = o3 * sigm(g.w);
        size_t oidx = (size_t)(c * 32 + q) * 128 + h * 32 + ds * 4;
        ushort4 hh, ll;
        hh.x = f2bf(ov.x); ll.x = f2bf(ov.x - bf2f(hh.x));
        hh.y = f2bf(ov.y); ll.y = f2bf(ov.y - bf2f(hh.y));
        hh.z = f2bf(ov.z); ll.z = f2bf(ov.z - bf2f(hh.z));
        hh.w = f2bf(ov.w); ll.w = f2bf(ov.w - bf2f(hh.w));
        *(ushort4*)(ogh + oidx) = hh;
        *(ushort4*)(ogl + oidx) = ll;
    }
}

extern "C" void kernel_launch(void* const* d_in, const int* in_sizes, int n_in,
                              void* d_out, int out_size, void* d_ws, size_t ws_size,
                              hipStream_t stream) {
    const float* ql = (const float*)d_in[0];
    const float* cl = (const float*)d_in[1];
    const float* plm = (const float*)d_in[2];
    const float* atom_mask = (const float*)d_in[3];
    const float* attn_gamma = (const float*)d_in[4];
    const float* attn_wsig = (const float*)d_in[5];
    const float* attn_bsig = (const float*)d_in[6];
    const float* attn_wskip = (const float*)d_in[7];
    const float* wq = (const float*)d_in[8];
    const float* bq = (const float*)d_in[9];
    const float* wk = (const float*)d_in[10];
    const float* wv = (const float*)d_in[11];
    const float* lnz_g = (const float*)d_in[12];
    const float* lnz_b = (const float*)d_in[13];
    const float* w_pair = (const float*)d_in[14];
    const float* w_gate = (const float*)d_in[15];
    const float* w_out = (const float*)d_in[16];
    const float* w_ao = (const float*)d_in[17];
    const float* b_ao = (const float*)d_in[18];
    const float* tr_gamma = (const float*)d_in[19];
    const float* tr_wsig = (const float*)d_in[20];
    const float* tr_bsig = (const float*)d_in[21];
    const float* tr_wskip = (const float*)d_in[22];
    const float* w_t1 = (const float*)d_in[23];
    const float* w_t2 = (const float*)d_in[24];
    const float* w_t3 = (const float*)d_in[25];
    const float* w_to = (const float*)d_in[26];
    const float* b_to = (const float*)d_in[27];
    float* out = (float*)d_out;
    float* ws = (float*)d_ws;

    // fp32 region
    float* sg = ws;                  // [3][6][NC]
    float* qkvg = ws + 18 * NC;      // [N][512]
    float* tbuf = ws + 22 * NC;      // [N][512]
    float* pb = ws + 26 * NC;        // [3][64][4][32][128]
    float* a_buf = ws + 38 * NC;     // [NC]
    float* Pbias = ws + 39 * NC;     // [3][6][128]
    // bf16 (u16) region
    u16* us = (u16*)(ws + 40 * NC);
    u16* lnsh = us;             u16* lnsl = us + NC;
    u16* clh = us + 2 * NC;     u16* cll = us + 3 * NC;
    u16* anh = us + 4 * NC;     u16* anl = us + 5 * NC;
    u16* tnh = us + 6 * NC;     u16* tnl = us + 7 * NC;
    u16* ogh = us + 8 * NC;     u16* ogl = us + 9 * NC;
    u16* swh = us + 10 * NC;    u16* swl = us + 12 * NC;   // [N][256] each
    u16* BP1h = us + 14 * NC;
    u16* BP1l = BP1h + 294912;
    u16* BG1h = BP1l + 294912;
    u16* BG1l = BG1h + 393216;
    u16* BG2h = BG1l + 393216;
    u16* BG2l = BG2h + 147456;

    prep_w<<<3273, 256, 0, stream>>>(attn_gamma, attn_wsig, attn_bsig, attn_wskip,
        wq, wk, wv, w_gate, w_out, w_ao, b_ao,
        tr_gamma, tr_wsig, tr_bsig, tr_wskip,
        w_t1, w_t2, w_t3, w_to, b_to,
        BP1h, BP1l, BG1h, BG1l, BG2h, BG2l, Pbias);
    ln_split<<<NA / 4, 256, 0, stream>>>(cl, lnsh, lnsl, clh, cll);
    mf_p1<<<dim3(64, 6, 3), 256, 0, stream>>>(lnsh, lnsl, clh, cll, BP1h, BP1l, Pbias, sg);
    pb_kernel<<<dim3(64, 16), 256, 0, stream>>>(plm, lnz_g, lnz_b, w_pair, pb);

    for (int i = 0; i < 3; ++i) {
        const float* a_cur = (i == 0) ? ql : a_buf;
        float* sgi = sg + (size_t)i * 6 * NC;
        an_tn<<<NA / 4, 256, 0, stream>>>(a_cur, sgi, anh, anl, tnh, tnl);
        mf_g1<<<dim3(64, 8), 256, 0, stream>>>(anh, anl, tnh, tnl,
            BG1h + (size_t)i * 131072, BG1l + (size_t)i * 131072,
            bq + (size_t)i * 128, qkvg, tbuf);
        attn_sw<<<dim3(64, 6), 256, 0, stream>>>(qkvg,
            pb + (size_t)i * 64 * 4 * 32 * 128, atom_mask, tbuf, ogh, ogl, swh, swl);
        float* dst = (i == 2) ? out : a_buf;
        mf_g2<<<64, 256, 0, stream>>>(ogh, ogl, swh, swl,
            BG2h + (size_t)i * 49152, BG2l + (size_t)i * 49152,
            sgi + 4 * NC, sgi + 5 * NC, dst);
    }
}